// Round 22
// baseline (23.836 us; speedup 1.0000x reference)
//
#include <hip/hip_runtime.h>
#include <hip/hip_bf16.h>
#include <cstdint>
#include <cstddef>

// Problem constants
#define Bsz 16384
#define Esz 16
#define Ssz 64
#define Asz 32
#define Isz 96   // S + A
#define HSz 64
#define HRz 32

#define NTM 256       // 4 waves
#define CHUNK 512     // batch rows per block
#define NTILE 8       // CHUNK / (4 waves * 16 rows)
#define NFRAG 26      // 12 W1 + 6 rW1 + 8 W2 fragments

typedef __attribute__((ext_vector_type(8))) short bf16x8;
typedef __attribute__((ext_vector_type(4))) short short4v;
typedef __attribute__((ext_vector_type(4))) float f32x4;

static __device__ __forceinline__ short f2bf(float f) {
    __hip_bfloat16 b = __float2bfloat16(f);   // pairs into v_cvt_pk_bf16_f32
    return *reinterpret_cast<short*>(&b);
}
static __device__ __forceinline__ float bf2f(short s) {
    union { uint32_t u; float f; } v; v.u = ((uint32_t)(uint16_t)s) << 16; return v.f;
}
static __device__ __forceinline__ bf16x8 pack8(float4 lo, float4 hi) {
    bf16x8 r;
    r[0] = f2bf(lo.x); r[1] = f2bf(lo.y); r[2] = f2bf(lo.z); r[3] = f2bf(lo.w);
    r[4] = f2bf(hi.x); r[5] = f2bf(hi.y); r[6] = f2bf(hi.z); r[7] = f2bf(hi.w);
    return r;
}

// R21 (best, 23.8 us) + OCCUPANCY EXPERIMENT:
//  - rW1/W2 fragments are NOT hoisted to registers; read from the (conflict-free,
//    fragment-ordered) WLf in-loop. Only W1 (the K=96 critical layer) stays in VGPRs.
//    Natural VGPR demand ~160 (was ~230).
//  - OT stride 72 -> 68 floats: LDS total 52736 B -> 3 blocks/CU possible.
// If the VGPR allocator is fine-grained, this yields 12 waves/CU (1.5x TLP).
// Steady-state structure otherwise identical to R21 (coop gather, swapped MFMA,
// XCD swizzle, rotating X prefetch, HT transpose, full-line nt-stores).
__global__ __launch_bounds__(NTM)
void fused_all(const float* __restrict__ state, const float* __restrict__ action,
               const float* __restrict__ W1, const float* __restrict__ b1,
               const float* __restrict__ W2, const float* __restrict__ b2,
               const float* __restrict__ rW1, const float* __restrict__ rb1,
               const float* __restrict__ rW2, const float* __restrict__ rb2,
               float* __restrict__ outS, float* __restrict__ outR)
{
    __shared__ __align__(16) short HT[4][16][68];      //  8704 B per-wave H transpose
    __shared__ __align__(16) float OT[4][16][68];      // 17408 B per-wave output staging
    __shared__ __align__(16) short WLf[NFRAG * 64 * 8];// 26624 B fragment-ordered weights
    // total 52736 B -> 3 blocks/CU (158.2 KB < 160 KB)

    // ---- XCD-aware sibling swizzle (bijective over 512 blocks) ----
    const int bid = blockIdx.x;
    const int xcd = bid & 7;
    const int rem = bid >> 3;
    const int e   = rem & (Esz - 1);
    const int c0  = (xcd + 8 * (rem >> 4)) * CHUNK;

    const int tid = threadIdx.x;
    const int w = tid >> 6, lane = tid & 63;
    const int lr = lane & 15, lg = lane >> 4;

    // ---- First X tile loads issued EARLY (latency overlaps the gather) ----
    const int row0 = c0 + w * 16 + lr;               // this lane's base batch row (m = lr)
    const float* sbase = state  + (size_t)row0 * Ssz + lg * 8;
    const float* abase = action + (size_t)row0 * Asz + lg * 8;
    float4 xs0 = *(const float4*)(sbase);
    float4 xs1 = *(const float4*)(sbase + 4);
    float4 xs2 = *(const float4*)(sbase + 32);
    float4 xs3 = *(const float4*)(sbase + 36);
    float4 xa0 = *(const float4*)(abase);
    float4 xa1 = *(const float4*)(abase + 4);

    // ---- Cooperative gather: 1664 fragment units split across 256 threads ----
    // Unit (f, l): 8 f32 loads in fragment order -> bf16x8 -> WLf[f*64 + l].
    // Fragment f: [0,12) W1 (f = nt*3+kk), [12,18) rW1, [18,26) W2.
    for (int u = tid; u < NFRAG * 64; u += NTM) {
        const int f = u >> 6, l = u & 63;
        const int llr = l & 15, llg = l >> 4;
        const float* p;
        int stride;
        if (f < 12) {
            int nt = f / 3, kk = f - nt * 3;
            p = W1 + (size_t)e * Isz * HSz + (kk * 32 + llg * 8) * HSz + nt * 16 + llr;
            stride = HSz;
        } else if (f < 18) {
            int f1 = f - 12;
            int nt = f1 / 3, kk = f1 - nt * 3;
            p = rW1 + (size_t)e * Isz * HRz + (kk * 32 + llg * 8) * HRz + nt * 16 + llr;
            stride = HRz;
        } else {
            int f1 = f - 18;
            int nt = f1 >> 1, kk = f1 & 1;
            p = W2 + (size_t)e * HSz * Ssz + (kk * 32 + llg * 8) * Ssz + nt * 16 + llr;
            stride = Ssz;
        }
        bf16x8 r;
        #pragma unroll
        for (int t = 0; t < 8; ++t) r[t] = f2bf(p[t * stride]);
        *(bf16x8*)&WLf[u * 8] = r;
    }

    // ---- Biases packed bf16 (lane's D slots: n = nt*16 + lg*4 + j) ----
    short4v b1p[4], b2p[4], rb1p[2], rw2p[2];
    #pragma unroll
    for (int nt = 0; nt < 4; ++nt) {
        float4 v1 = *(const float4*)&b1[e * HSz + nt * 16 + lg * 4];
        float4 v2 = *(const float4*)&b2[e * Ssz + nt * 16 + lg * 4];
        b1p[nt] = (short4v){ f2bf(v1.x), f2bf(v1.y), f2bf(v1.z), f2bf(v1.w) };
        b2p[nt] = (short4v){ f2bf(v2.x), f2bf(v2.y), f2bf(v2.z), f2bf(v2.w) };
    }
    #pragma unroll
    for (int nt = 0; nt < 2; ++nt) {
        float4 v1 = *(const float4*)&rb1[e * HRz + nt * 16 + lg * 4];
        float4 v2 = *(const float4*)&rW2[e * HRz + nt * 16 + lg * 4];
        rb1p[nt] = (short4v){ f2bf(v1.x), f2bf(v1.y), f2bf(v1.z), f2bf(v1.w) };
        rw2p[nt] = (short4v){ f2bf(v2.x), f2bf(v2.y), f2bf(v2.z), f2bf(v2.w) };
    }
    const float rb2s = rb2[e];

    __syncthreads();   // WLf staged

    // ---- Only W1 fragments hoisted to registers (K=96 critical layer) ----
    bf16x8 w1r[4][3];
    #pragma unroll
    for (int nt = 0; nt < 4; ++nt)
        #pragma unroll
        for (int kk = 0; kk < 3; ++kk)
            w1r[nt][kk] = *(const bf16x8*)&WLf[((nt * 3 + kk) * 64 + lane) * 8];

    // ---- Pack first A-fragments (loads issued before gather) ----
    bf16x8 a0 = pack8(xs0, xs1);
    bf16x8 a1 = pack8(xs2, xs3);
    bf16x8 a2 = pack8(xa0, xa1);

    #pragma unroll 1
    for (int t = 0; t < NTILE; ++t) {
        // Prefetch next tile's f32 rows (wraps on last iter; L2-hit, discarded)
        const int tn = (t + 1) & (NTILE - 1);
        const float* sp = sbase + (size_t)tn * 64 * Ssz;
        const float* ap = abase + (size_t)tn * 64 * Asz;
        float4 ns0 = *(const float4*)(sp);
        float4 ns1 = *(const float4*)(sp + 4);
        float4 ns2 = *(const float4*)(sp + 32);
        float4 ns3 = *(const float4*)(sp + 36);
        float4 na0 = *(const float4*)(ap);
        float4 na1 = *(const float4*)(ap + 4);

        // ---- Layer 1 (state): W1 from registers, acc init = bias ----
        f32x4 accS[4];
        #pragma unroll
        for (int nt = 0; nt < 4; ++nt) {
            f32x4 acc = (f32x4){ bf2f(b1p[nt][0]), bf2f(b1p[nt][1]),
                                 bf2f(b1p[nt][2]), bf2f(b1p[nt][3]) };
            acc = __builtin_amdgcn_mfma_f32_16x16x32_bf16(w1r[nt][0], a0, acc, 0, 0, 0);
            acc = __builtin_amdgcn_mfma_f32_16x16x32_bf16(w1r[nt][1], a1, acc, 0, 0, 0);
            acc = __builtin_amdgcn_mfma_f32_16x16x32_bf16(w1r[nt][2], a2, acc, 0, 0, 0);
            accS[nt] = acc;
        }
        // ---- Layer 1 (reward): fragments streamed from WLf (conflict-free) ----
        f32x4 accR[2];
        #pragma unroll
        for (int nt = 0; nt < 2; ++nt) {
            f32x4 acc = (f32x4){ bf2f(rb1p[nt][0]), bf2f(rb1p[nt][1]),
                                 bf2f(rb1p[nt][2]), bf2f(rb1p[nt][3]) };
            acc = __builtin_amdgcn_mfma_f32_16x16x32_bf16(
                      *(const bf16x8*)&WLf[((12 + nt * 3 + 0) * 64 + lane) * 8], a0, acc, 0, 0, 0);
            acc = __builtin_amdgcn_mfma_f32_16x16x32_bf16(
                      *(const bf16x8*)&WLf[((12 + nt * 3 + 1) * 64 + lane) * 8], a1, acc, 0, 0, 0);
            acc = __builtin_amdgcn_mfma_f32_16x16x32_bf16(
                      *(const bf16x8*)&WLf[((12 + nt * 3 + 2) * 64 + lane) * 8], a2, acc, 0, 0, 0);
            accR[nt] = acc;
        }

        // ---- H = relu(accS) -> HT (lane holds 4 consecutive h of row lr) ----
        #pragma unroll
        for (int nt = 0; nt < 4; ++nt) {
            short4v p = { f2bf(fmaxf(accS[nt][0], 0.f)),
                          f2bf(fmaxf(accS[nt][1], 0.f)),
                          f2bf(fmaxf(accS[nt][2], 0.f)),
                          f2bf(fmaxf(accS[nt][3], 0.f)) };
            *(short4v*)&HT[w][lr][nt * 16 + lg * 4] = p;
        }

        // ---- Reward layer 2 in registers ----
        float rp = 0.f;
        #pragma unroll
        for (int nt = 0; nt < 2; ++nt) {
            rp += fmaxf(accR[nt][0], 0.f) * bf2f(rw2p[nt][0]);
            rp += fmaxf(accR[nt][1], 0.f) * bf2f(rw2p[nt][1]);
            rp += fmaxf(accR[nt][2], 0.f) * bf2f(rw2p[nt][2]);
            rp += fmaxf(accR[nt][3], 0.f) * bf2f(rw2p[nt][3]);
        }
        rp += __shfl_xor(rp, 16);
        rp += __shfl_xor(rp, 32);
        if (lane < 16)
            __builtin_nontemporal_store(fminf(fmaxf(rp + rb2s, -100.f), 200.f),
                                        &outR[(size_t)e * Bsz + row0 + t * 64]);

        // ---- Layer 2 (state): H via b128; W2 fragments streamed from WLf ----
        bf16x8 h0 = *(const bf16x8*)&HT[w][lr][lg * 8];
        bf16x8 h1 = *(const bf16x8*)&HT[w][lr][32 + lg * 8];
        #pragma unroll
        for (int nt = 0; nt < 4; ++nt) {
            f32x4 acc = (f32x4){ bf2f(b2p[nt][0]), bf2f(b2p[nt][1]),
                                 bf2f(b2p[nt][2]), bf2f(b2p[nt][3]) };
            acc = __builtin_amdgcn_mfma_f32_16x16x32_bf16(
                      *(const bf16x8*)&WLf[((18 + nt * 2 + 0) * 64 + lane) * 8], h0, acc, 0, 0, 0);
            acc = __builtin_amdgcn_mfma_f32_16x16x32_bf16(
                      *(const bf16x8*)&WLf[((18 + nt * 2 + 1) * 64 + lane) * 8], h1, acc, 0, 0, 0);
            *(f32x4*)&OT[w][lr][nt * 16 + lg * 4] = acc;
        }
        // ---- Full-line coalesced stores: wave's 4 KB region as 4 x 1KB nt ----
        {
            const size_t obase = ((size_t)e * Bsz + c0 + t * 64 + w * 16) * Ssz;
            #pragma unroll
            for (int q = 0; q < 4; ++q) {
                f32x4 v = *(const f32x4*)&OT[w][4 * q + (lane >> 4)][(lane & 15) * 4];
                __builtin_nontemporal_store(v, (f32x4*)&outS[obase + q * 256 + lane * 4]);
            }
        }

        // ---- Convert prefetched f32 -> current fragments (vmcnt wait lands here) ----
        a0 = pack8(ns0, ns1);
        a1 = pack8(ns2, ns3);
        a2 = pack8(na0, na1);
    }
}

extern "C" void kernel_launch(void* const* d_in, const int* in_sizes, int n_in,
                              void* d_out, int out_size, void* d_ws, size_t ws_size,
                              hipStream_t stream) {
    const float* state  = (const float*)d_in[0];
    const float* action = (const float*)d_in[1];
    const float* W1  = (const float*)d_in[2];
    const float* b1  = (const float*)d_in[3];
    const float* W2  = (const float*)d_in[4];
    const float* b2  = (const float*)d_in[5];
    const float* rW1 = (const float*)d_in[6];
    const float* rb1 = (const float*)d_in[7];
    const float* rW2 = (const float*)d_in[8];
    const float* rb2 = (const float*)d_in[9];

    float* outS = (float*)d_out;                      // [E, B, S]
    float* outR = outS + (size_t)Esz * Bsz * Ssz;     // [E, B, 1]

    fused_all<<<Esz * (Bsz / CHUNK), NTM, 0, stream>>>(   // 512 blocks
        state, action, W1, b1, W2, b2, rW1, rb1, rW2, rb2, outS, outR);
}